// Round 1
// baseline (812.771 us; speedup 1.0000x reference)
//
#include <hip/hip_runtime.h>
#include <hip/hip_bf16.h>
#include <math.h>

typedef unsigned int u32;
typedef unsigned long long u64;

#define PRE_NMS   6000
#define NWORDS    94        /* ceil(6000/64) */
#define WSTRIDE   96        /* padded u64 words per mask row */
#define HIST_WORDS 1048576  /* bits>>10 buckets, covers (0,1) floats */
#define TOP_BUCKET 1040384  /* 0x3F800000 >> 10 */

/* ws byte offsets */
#define HIST_OFF 0
#define CTR_OFF  4194304            /* 64 u32: [0]=cand counter [1]=pivot bits */
#define CAND_OFF 4194560            /* 8192 u64 keys */
#define BOX_OFF  4260096            /* 6000 float4 (group-offset boxes) */
#define AREA_OFF 4356096            /* 6000 float */
#define DIAG_OFF 4380160            /* 6016 u64 diagonal words */
#define MASK_OFF 4428288            /* (6016*96 + 64) u64 suppression matrix */

__global__ void zero_kernel(uint4* __restrict__ p, int n4) {
    int idx = blockIdx.x * blockDim.x + threadIdx.x;
    int stride = gridDim.x * blockDim.x;
    uint4 z; z.x = z.y = z.z = z.w = 0u;
    for (int i = idx; i < n4; i += stride) p[i] = z;
}

__global__ void hist_kernel(const float* __restrict__ probs, u32* __restrict__ hist, int nfg) {
    int i = blockIdx.x * blockDim.x + threadIdx.x;
    if (i >= nfg) return;
    float v = probs[(i >> 1) * 3 + 1 + (i & 1)];
    u32 bits = __float_as_uint(v);
    u32 b = bits >> 10; if (b >= HIST_WORDS) b = HIST_WORDS - 1;
    atomicAdd(&hist[b], 1u);
}

__global__ __launch_bounds__(1024) void pivot_kernel(const u32* __restrict__ hist, u32* ctr) {
    __shared__ u32 sd[1024];
    __shared__ u32 s_cum;
    __shared__ int s_found;
    int tid = threadIdx.x;
    if (tid == 0) { s_cum = 0u; s_found = 0; }
    __syncthreads();
    for (int base = 0; base < TOP_BUCKET + 2048; base += 1024) {
        int bucket = TOP_BUCKET - base - tid;
        u32 v = (bucket >= 0) ? hist[bucket] : 0u;
        sd[tid] = v;
        __syncthreads();
        for (int off = 1; off < 1024; off <<= 1) {
            u32 t = (tid >= off) ? sd[tid - off] : 0u;
            __syncthreads();
            sd[tid] += t;
            __syncthreads();
        }
        u32 incl = sd[tid];
        u32 cum = s_cum;
        if (bucket >= 0 && cum + incl >= (u32)PRE_NMS && cum + incl - v < (u32)PRE_NMS) {
            ctr[1] = ((u32)bucket) << 10;   /* pivot bits: candidates are bits >= this */
            s_found = 1;
        }
        __syncthreads();
        if (s_found) return;
        if (tid == 0) s_cum = cum + sd[1023];
        __syncthreads();
    }
}

__global__ void compact_kernel(const float* __restrict__ probs, u32* ctr,
                               u64* __restrict__ cand, int nfg) {
    int i = blockIdx.x * blockDim.x + threadIdx.x;
    if (i >= nfg) return;
    u32 pivot = ctr[1];
    float v = probs[(i >> 1) * 3 + 1 + (i & 1)];
    u32 bits = __float_as_uint(v);
    if (bits >= pivot) {
        u32 pos = atomicAdd(&ctr[0], 1u);
        if (pos < 8192u) cand[pos] = ((u64)bits << 32) | (u64)(~(u32)i);
    }
}

__global__ __launch_bounds__(1024) void sort_kernel(u64* cand, const u32* __restrict__ ctr) {
    __shared__ u64 K[8192];   /* 64 KiB */
    int tid = threadIdx.x;
    u32 n = ctr[0]; if (n > 8192u) n = 8192u;
    for (int s = tid; s < 8192; s += 1024) K[s] = ((u32)s < n) ? cand[s] : 0ull;
    for (int k = 2; k <= 8192; k <<= 1) {
        for (int j = k >> 1; j > 0; j >>= 1) {
            __syncthreads();
            #pragma unroll
            for (int m = 0; m < 8; ++m) {
                int idx = (m << 10) | tid;
                int p = idx ^ j;
                if (p > idx) {
                    u64 a = K[idx], b = K[p];
                    bool desc = ((idx & k) == 0);
                    bool sw = desc ? (a < b) : (a > b);
                    if (sw) { K[idx] = b; K[p] = a; }
                }
            }
        }
    }
    __syncthreads();
    for (int s = tid; s < 8192; s += 1024) cand[s] = K[s];
}

__global__ void rois_kernel(const u64* __restrict__ skeys,
                            const float4* __restrict__ deltas4,
                            const float4* __restrict__ anchors4,
                            float* __restrict__ out,
                            float4* __restrict__ boxes,
                            float* __restrict__ areas,
                            int n_anch) {
    int s = blockIdx.x * blockDim.x + threadIdx.x;
    if (s >= PRE_NMS) return;
    u64 key = skeys[s];
    u32 bits = (u32)(key >> 32);
    u32 flat = ~((u32)key);
    float score = __uint_as_float(bits);
    int p = (int)(flat >> 1);
    int cls = (int)(flat & 1u) + 1;
    int b = p / n_anch;
    int aidx = p - b * n_anch;
    float4 a = anchors4[aidx];
    float4 d = deltas4[p];
    float d0 = d.x * 0.1f, d1 = d.y * 0.1f, d2 = d.z * 0.2f, d3 = d.w * 0.2f;
    float y1 = a.x * (1.0f / 512.0f), x1 = a.y * (1.0f / 512.0f);
    float y2 = a.z * (1.0f / 512.0f), x2 = a.w * (1.0f / 512.0f);
    float h = y2 - y1, w = x2 - x1;
    float cy = y1 + 0.5f * h + d0 * h;
    float cx = x1 + 0.5f * w + d1 * w;
    h = h * expf(d2);
    w = w * expf(d3);
    float ry1 = (cy - 0.5f * h) * 512.0f;
    float rx1 = (cx - 0.5f * w) * 512.0f;
    float ry2 = (cy - 0.5f * h + h) * 512.0f;
    float rx2 = (cx - 0.5f * w + w) * 512.0f;
    ry1 = fminf(fmaxf(ry1, 0.0f), 512.0f);
    rx1 = fminf(fmaxf(rx1, 0.0f), 512.0f);
    ry2 = fminf(fmaxf(ry2, 0.0f), 512.0f);
    rx2 = fminf(fmaxf(rx2, 0.0f), 512.0f);
    out[s * 6 + 0] = ry1;
    out[s * 6 + 1] = rx1;
    out[s * 6 + 2] = ry2;
    out[s * 6 + 3] = rx2;
    out[s * 6 + 4] = score;
    out[PRE_NMS * 6 + s] = (float)cls;
    out[PRE_NMS * 7 + s] = (float)b;
    float g = (float)(b * 3 + cls) * 4096.0f;
    float4 bb = make_float4(ry1 + g, rx1 + g, ry2 + g, rx2 + g);
    boxes[s] = bb;
    areas[s] = (bb.z - bb.x + 1.0f) * (bb.w - bb.y + 1.0f);
}

__global__ void mask_kernel(const float4* __restrict__ boxes,
                            const float* __restrict__ areas,
                            u64* __restrict__ mask,
                            u64* __restrict__ diag) {
    int rb = blockIdx.y, cb = blockIdx.x;
    if (cb < rb) return;
    __shared__ float4 cbox[64];
    __shared__ float car[64];
    int t = threadIdx.x;
    int j0 = cb * 64;
    int jj = j0 + t;
    if (jj < PRE_NMS) { cbox[t] = boxes[jj]; car[t] = areas[jj]; }
    else { cbox[t] = make_float4(-1e30f, -1e30f, -1e30f, -1e30f); car[t] = 3e38f; }
    __syncthreads();
    int i = rb * 64 + t;
    if (i >= PRE_NMS) return;
    float4 bi = boxes[i];
    float ai = areas[i];
    u64 word = 0ull;
    #pragma unroll
    for (int q = 0; q < 64; ++q) {
        float4 bj = cbox[q];
        float ih = fminf(bi.z, bj.z) - fmaxf(bi.x, bj.x) + 1.0f;
        float iw = fminf(bi.w, bj.w) - fmaxf(bi.y, bj.y) + 1.0f;
        ih = fmaxf(ih, 0.0f); iw = fmaxf(iw, 0.0f);
        float inter = ih * iw;
        /* iou >= 0.5  <=>  3*inter >= ai + aj   (boundary fp flips only hit keep col, tol 10.24) */
        bool over = (3.0f * inter >= ai + car[q]);
        int j = j0 + q;
        if (over && (j > i)) word |= (1ull << q);
    }
    mask[i * WSTRIDE + cb] = word;
    if (cb == rb) diag[i] = word;
}

__global__ __launch_bounds__(64) void nms_serial_kernel(const u64* __restrict__ mask,
                                                        const u64* __restrict__ diag,
                                                        float* __restrict__ out) {
    int lane = threadIdx.x;
    u64 remv0 = 0ull, remv1 = 0ull;
    for (int w = 0; w < NWORDS; ++w) {
        /* broadcast current remv word w to all lanes (once per 64 rows) */
        u64 c0 = __shfl(remv0, w & 63);
        u64 c1 = __shfl(remv1, (w >= 64) ? (w - 64) : 0);
        u64 cur = (w < 64) ? c0 : c1;
        const u64* rowbase = mask + (u64)w * 64 * WSTRIDE;
        const u64* dgbase = diag + w * 64;
        u64 kb = 0ull;   /* keep bits, replicated across lanes */
        #pragma unroll 16
        for (int b = 0; b < 64; ++b) {
            /* unconditional loads: independent of serial chain, prefetchable */
            u64 m0 = rowbase[b * WSTRIDE + lane];
            u64 m1 = rowbase[b * WSTRIDE + 64 + lane];
            u64 dg = dgbase[b];             /* uniform address */
            bool sup = (cur >> b) & 1ull;
            u64 km = sup ? 0ull : ~0ull;
            cur |= dg & km;
            remv0 |= m0 & km;
            remv1 |= m1 & km;
            kb |= km & (1ull << b);
        }
        int i = w * 64 + lane;
        if (i < PRE_NMS)
            out[i * 6 + 5] = ((kb >> lane) & 1ull) ? 1.0f : 0.0f;
    }
}

extern "C" void kernel_launch(void* const* d_in, const int* in_sizes, int n_in,
                              void* d_out, int out_size, void* d_ws, size_t ws_size,
                              hipStream_t stream) {
    const float* probs   = (const float*)d_in[0];
    const float* deltas  = (const float*)d_in[1];
    const float* anchors = (const float*)d_in[2];
    int n_prop = in_sizes[1] / 4;        /* 522240 */
    int n_anch = in_sizes[2] / 4;        /* 65280  */
    int nfg    = n_prop * 2;             /* 1044480 */

    char* ws = (char*)d_ws;
    u32*    hist  = (u32*)(ws + HIST_OFF);
    u32*    ctr   = (u32*)(ws + CTR_OFF);
    u64*    cand  = (u64*)(ws + CAND_OFF);
    float4* boxes = (float4*)(ws + BOX_OFF);
    float*  areas = (float*)(ws + AREA_OFF);
    u64*    diag  = (u64*)(ws + DIAG_OFF);
    u64*    mask  = (u64*)(ws + MASK_OFF);
    float*  out   = (float*)d_out;

    /* zero hist + counters: (1048576 + 64) u32 = 262160 uint4 */
    zero_kernel<<<1024, 256, 0, stream>>>((uint4*)(ws + HIST_OFF), 262160);
    hist_kernel<<<(nfg + 255) / 256, 256, 0, stream>>>(probs, hist, nfg);
    pivot_kernel<<<1, 1024, 0, stream>>>(hist, ctr);
    compact_kernel<<<(nfg + 255) / 256, 256, 0, stream>>>(probs, ctr, cand, nfg);
    sort_kernel<<<1, 1024, 0, stream>>>(cand, ctr);
    rois_kernel<<<(PRE_NMS + 255) / 256, 256, 0, stream>>>(
        cand, (const float4*)deltas, (const float4*)anchors, out, boxes, areas, n_anch);
    mask_kernel<<<dim3(NWORDS, NWORDS), 64, 0, stream>>>(boxes, areas, mask, diag);
    nms_serial_kernel<<<1, 64, 0, stream>>>(mask, diag, out);
}

// Round 2
// 503.984 us; speedup vs baseline: 1.6127x; 1.6127x over previous
//
#include <hip/hip_runtime.h>
#include <hip/hip_bf16.h>
#include <math.h>

typedef unsigned int u32;
typedef unsigned long long u64;

#define PRE_NMS    6000
#define NGROUPS    24       /* batch(8) * (n_fg+1=3) group ids; only b*3+{1,2} occur */
#define HIST_WORDS 1048576  /* bits>>10 buckets */
#define TOP_BUCKET 1040384  /* 0x3F800000 >> 10 */

/* ws byte offsets (total ~9.0 MB, within round-1 footprint) */
#define HIST_OFF  0
#define CTR_OFF   4194304   /* 64 u32: [0]=cand count [1]=pivot bits [2]=gmask bump */
#define CAND_OFF  4194560   /* 8192 u64 unsorted candidate keys */
#define RANK_OFF  4260096   /* 8192 u64 rank-scattered (sorted) keys */
#define BOX_OFF   4325632   /* 6000 float4 group-offset boxes */
#define AREA_OFF  4421632   /* 6000 float */
#define GID_OFF   4445632   /* 6000 int group ids */
#define GMASK_OFF 4469632   /* per-group mask slices, bump-allocated (<=4.54 MB) */

__global__ void zero_kernel(uint4* __restrict__ p, int n4) {
    int idx = blockIdx.x * blockDim.x + threadIdx.x;
    int stride = gridDim.x * blockDim.x;
    uint4 z; z.x = z.y = z.z = z.w = 0u;
    for (int i = idx; i < n4; i += stride) p[i] = z;
}

__global__ void hist_kernel(const float* __restrict__ probs, u32* __restrict__ hist, int nfg) {
    int i = blockIdx.x * blockDim.x + threadIdx.x;
    if (i >= nfg) return;
    float v = probs[(i >> 1) * 3 + 1 + (i & 1)];
    u32 bits = __float_as_uint(v);
    u32 b = bits >> 10; if (b >= HIST_WORDS) b = HIST_WORDS - 1;
    atomicAdd(&hist[b], 1u);
}

__global__ __launch_bounds__(1024) void pivot_kernel(const u32* __restrict__ hist, u32* ctr) {
    __shared__ u32 sd[1024];
    __shared__ u32 s_cum;
    __shared__ int s_found;
    int tid = threadIdx.x;
    if (tid == 0) { s_cum = 0u; s_found = 0; }
    __syncthreads();
    for (int base = 0; base < TOP_BUCKET + 2048; base += 1024) {
        int bucket = TOP_BUCKET - base - tid;
        u32 v = (bucket >= 0) ? hist[bucket] : 0u;
        sd[tid] = v;
        __syncthreads();
        for (int off = 1; off < 1024; off <<= 1) {
            u32 t = (tid >= off) ? sd[tid - off] : 0u;
            __syncthreads();
            sd[tid] += t;
            __syncthreads();
        }
        u32 incl = sd[tid];
        u32 cum = s_cum;
        if (bucket >= 0 && cum + incl >= (u32)PRE_NMS && cum + incl - v < (u32)PRE_NMS) {
            ctr[1] = ((u32)bucket) << 10;
            s_found = 1;
        }
        __syncthreads();
        if (s_found) return;
        if (tid == 0) s_cum = cum + sd[1023];
        __syncthreads();
    }
}

__global__ void compact_kernel(const float* __restrict__ probs, u32* ctr,
                               u64* __restrict__ cand, int nfg) {
    int i = blockIdx.x * blockDim.x + threadIdx.x;
    if (i >= nfg) return;
    u32 pivot = ctr[1];
    float v = probs[(i >> 1) * 3 + 1 + (i & 1)];
    u32 bits = __float_as_uint(v);
    if (bits >= pivot) {
        u32 pos = atomicAdd(&ctr[0], 1u);
        if (pos < 8192u) cand[pos] = ((u64)bits << 32) | (u64)(~(u32)i);
    }
}

/* exact descending stable position via rank-by-counting (keys unique) */
__global__ __launch_bounds__(256) void rank_kernel(const u64* __restrict__ cand,
                                                   const u32* __restrict__ ctr,
                                                   u64* __restrict__ ranked) {
    __shared__ u64 tile[256];
    int t = threadIdx.x;
    int i = blockIdx.x * 256 + t;
    u32 M = ctr[0]; if (M > 8192u) M = 8192u;
    u64 key = (i < (int)M) ? cand[i] : 0ull;
    int rank = 0;
    for (u32 base = 0; base < M; base += 256) {
        u32 s = base + t;
        tile[t] = (s < M) ? cand[s] : 0ull;  /* 0 pad: real keys have bits>=pivot>0 */
        __syncthreads();
        #pragma unroll 8
        for (int q = 0; q < 256; ++q) rank += (tile[q] > key) ? 1 : 0;
        __syncthreads();
    }
    if (i < (int)M && rank < PRE_NMS) ranked[rank] = key;
}

__global__ void rois_kernel(const u64* __restrict__ skeys,
                            const float4* __restrict__ deltas4,
                            const float4* __restrict__ anchors4,
                            float* __restrict__ out,
                            float4* __restrict__ boxes,
                            float* __restrict__ areas,
                            int* __restrict__ gid,
                            int n_anch) {
    int s = blockIdx.x * blockDim.x + threadIdx.x;
    if (s >= PRE_NMS) return;
    u64 key = skeys[s];
    u32 bits = (u32)(key >> 32);
    u32 flat = ~((u32)key);
    float score = __uint_as_float(bits);
    int p = (int)(flat >> 1);
    int cls = (int)(flat & 1u) + 1;
    int b = p / n_anch;
    int aidx = p - b * n_anch;
    float4 a = anchors4[aidx];
    float4 d = deltas4[p];
    float d0 = d.x * 0.1f, d1 = d.y * 0.1f, d2 = d.z * 0.2f, d3 = d.w * 0.2f;
    float y1 = a.x * (1.0f / 512.0f), x1 = a.y * (1.0f / 512.0f);
    float y2 = a.z * (1.0f / 512.0f), x2 = a.w * (1.0f / 512.0f);
    float h = y2 - y1, w = x2 - x1;
    float cy = y1 + 0.5f * h + d0 * h;
    float cx = x1 + 0.5f * w + d1 * w;
    h = h * expf(d2);
    w = w * expf(d3);
    float ry1 = (cy - 0.5f * h) * 512.0f;
    float rx1 = (cx - 0.5f * w) * 512.0f;
    float ry2 = (cy - 0.5f * h + h) * 512.0f;
    float rx2 = (cx - 0.5f * w + w) * 512.0f;
    ry1 = fminf(fmaxf(ry1, 0.0f), 512.0f);
    rx1 = fminf(fmaxf(rx1, 0.0f), 512.0f);
    ry2 = fminf(fmaxf(ry2, 0.0f), 512.0f);
    rx2 = fminf(fmaxf(rx2, 0.0f), 512.0f);
    out[s * 6 + 0] = ry1;
    out[s * 6 + 1] = rx1;
    out[s * 6 + 2] = ry2;
    out[s * 6 + 3] = rx2;
    out[s * 6 + 4] = score;
    out[PRE_NMS * 6 + s] = (float)cls;
    out[PRE_NMS * 7 + s] = (float)b;
    int g = b * 3 + cls;
    float gf = (float)g * 4096.0f;
    float4 bb = make_float4(ry1 + gf, rx1 + gf, ry2 + gf, rx2 + gf);
    boxes[s] = bb;
    areas[s] = (bb.z - bb.x + 1.0f) * (bb.w - bb.y + 1.0f);
    gid[s] = g;
}

/* One block per (batch,class) group. Cross-group IoU is exactly 0
   (GROUP_OFFSET=4096 >> 512 box extent), so per-group greedy NMS == global. */
__global__ __launch_bounds__(256) void group_nms_kernel(const float4* __restrict__ boxes,
                                                        const float* __restrict__ areas,
                                                        const int* __restrict__ gid,
                                                        u32* __restrict__ ctr,
                                                        u64* __restrict__ gmask_region,
                                                        float* __restrict__ out) {
    __shared__ int list[PRE_NMS];    /* 24 KB: group members in global score order */
    __shared__ u64 sdiag[PRE_NMS > 4096 ? PRE_NMS : 4096]; /* 48 KB diag words */
    __shared__ int sK, sBase;
    int g = blockIdx.x;
    int t = threadIdx.x;
    int lane = t & 63;

    /* Phase A: stable compaction of this group's members (wave 0) */
    if (t < 64) {
        int k = 0;
        for (int base = 0; base < PRE_NMS; base += 64) {
            int s = base + lane;
            bool f = (s < PRE_NMS) && (gid[s] == g);
            u64 bal = __ballot(f);
            if (f) list[k + (int)__popcll(bal & ((1ull << lane) - 1ull))] = s;
            k += (int)__popcll(bal);
        }
        if (lane == 0) sK = k;
    }
    __syncthreads();
    int K = sK;
    int W = (K + 63) >> 6;
    if (t == 0) sBase = (K > 0) ? (int)atomicAdd(&ctr[2], (u32)(K * W + 128)) : 0;
    __syncthreads();
    u64* gm = gmask_region + sBase;

    /* Phase B: all 256 threads build the KxW suppression bitmask */
    for (int item = t; item < K * W; item += 256) {
        int r = item / W;
        int c = item - r * W;
        int i = list[r];
        float4 bi = boxes[i];
        float ai = areas[i];
        u64 word = 0ull;
        int j0 = c << 6;
        int qs = r + 1 - j0; if (qs < 0) qs = 0;
        int qe = K - j0; if (qe > 64) qe = 64;
        for (int q = qs; q < qe; ++q) {
            int j = list[j0 + q];
            float4 bj = boxes[j];
            float ih = fminf(bi.z, bj.z) - fmaxf(bi.x, bj.x) + 1.0f;
            float iw = fminf(bi.w, bj.w) - fmaxf(bi.y, bj.y) + 1.0f;
            ih = fmaxf(ih, 0.0f); iw = fmaxf(iw, 0.0f);
            float inter = ih * iw;
            /* iou>=0.5 <=> 3*inter >= ai+aj */
            if (3.0f * inter >= ai + areas[j]) word |= (1ull << q);
        }
        gm[item] = word;
        if (c == (r >> 6)) sdiag[r] = word;  /* diagonal word: off the global-latency chain */
    }
    __syncthreads();

    /* Phase C: serial bit-chain over K rows (wave 0); remv word q lives in lane q */
    if (t < 64) {
        u64 remv0 = 0ull, remv1 = 0ull;
        bool wgt64 = (W > 64);
        for (int w = 0; w < W; ++w) {
            u64 c0 = __shfl(remv0, w & 63);
            u64 c1 = __shfl(remv1, (w >= 64) ? (w - 64) : 0);
            u64 cur = (w < 64) ? c0 : c1;
            int r0 = w << 6;
            int rend = K - r0; if (rend > 64) rend = 64;
            u64 kb = 0ull;
            for (int b = 0; b < rend; ++b) {
                const u64* row = gm + (u64)(r0 + b) * W;
                u64 m0 = row[lane];                  /* lanes >= W read pad: harmless */
                u64 m1 = wgt64 ? row[64 + lane] : 0ull;
                u64 dg = sdiag[r0 + b];              /* LDS, prefetchable */
                u64 km = ((cur >> b) & 1ull) ? 0ull : ~0ull;
                cur |= dg & km;
                remv0 |= m0 & km;
                remv1 |= m1 & km;
                kb |= km & (1ull << b);
            }
            if (lane < rend)
                out[list[r0 + lane] * 6 + 5] = ((kb >> lane) & 1ull) ? 1.0f : 0.0f;
        }
    }
}

extern "C" void kernel_launch(void* const* d_in, const int* in_sizes, int n_in,
                              void* d_out, int out_size, void* d_ws, size_t ws_size,
                              hipStream_t stream) {
    const float* probs   = (const float*)d_in[0];
    const float* deltas  = (const float*)d_in[1];
    const float* anchors = (const float*)d_in[2];
    int n_prop = in_sizes[1] / 4;        /* 522240 */
    int n_anch = in_sizes[2] / 4;        /* 65280  */
    int nfg    = n_prop * 2;             /* 1044480 */

    char* ws = (char*)d_ws;
    u32*    hist   = (u32*)(ws + HIST_OFF);
    u32*    ctr    = (u32*)(ws + CTR_OFF);
    u64*    cand   = (u64*)(ws + CAND_OFF);
    u64*    ranked = (u64*)(ws + RANK_OFF);
    float4* boxes  = (float4*)(ws + BOX_OFF);
    float*  areas  = (float*)(ws + AREA_OFF);
    int*    gid    = (int*)(ws + GID_OFF);
    u64*    gmask  = (u64*)(ws + GMASK_OFF);
    float*  out    = (float*)d_out;

    /* zero hist + ctr: (1048576 + 64) u32 = 262160 uint4 */
    zero_kernel<<<1024, 256, 0, stream>>>((uint4*)(ws + HIST_OFF), 262160);
    hist_kernel<<<(nfg + 255) / 256, 256, 0, stream>>>(probs, hist, nfg);
    pivot_kernel<<<1, 1024, 0, stream>>>(hist, ctr);
    compact_kernel<<<(nfg + 255) / 256, 256, 0, stream>>>(probs, ctr, cand, nfg);
    rank_kernel<<<32, 256, 0, stream>>>(cand, ctr, ranked);
    rois_kernel<<<(PRE_NMS + 255) / 256, 256, 0, stream>>>(
        ranked, (const float4*)deltas, (const float4*)anchors, out, boxes, areas, gid, n_anch);
    group_nms_kernel<<<NGROUPS, 256, 0, stream>>>(boxes, areas, gid, ctr, gmask, out);
}